// Round 18
// baseline (133.212 us; speedup 1.0000x reference)
//
#include <hip/hip_runtime.h>

#define NB 64      // batch
#define SEQ 305    // sequence length
#define DIM 2048   // hidden
#define NP 256     // patches
#define NT 48      // task tokens
#define NKEEP 128  // kept patches
#define SOUT 177   // 1 + 128 + 48
#define NCOPY 8    // copy blocks per batch

static_assert(1 + NP + NT == SEQ, "layout");

constexpr float kScale = 0.022097086912079608f;  // 1/sqrt(2048)

typedef _Float16 f16;
typedef __attribute__((ext_vector_type(8))) _Float16 f16x8;
typedef __attribute__((ext_vector_type(4))) float f32x4;

// ---------------------------------------------------------------------------
// K1a: split-f16 MFMA partial GEMM (R13/R15/R17-validated core, depth-1
// staging). grid (ndc+NCOPY, 64), 256 thr. ndc=16 -> 1024 GEMM blocks
// (4/CU queued vs R17's 2/CU) for latency hiding; per-thread code identical
// (nchunk = 4). x >= ndc: 1/8 of the static cls+task copy.
// Error ~5e-7 relative -- proven selection-exact R13-R17 (absmax = 0).
// ---------------------------------------------------------------------------
union KSMem {
  f16 stage[304 * 72];   // 43,776 B
  float rt[48 * 260];    // 49,920 B
};

__global__ __launch_bounds__(256) void k1a_partial_gemm(
    const float* __restrict__ tokens, float* __restrict__ rpart,
    float* __restrict__ ssqP, float* __restrict__ ssqT,
    float* __restrict__ out0, int ndc, int dchunk) {
  const int b = blockIdx.y;
  const int t = threadIdx.x;

  if ((int)blockIdx.x >= ndc) {
    // copy cls (row 0 -> 0) and task rows (257..304 -> 129..176), 49 rows
    // split 6/.../7 across NCOPY blocks.
    const int ci = blockIdx.x - ndc;  // 0..7
    const int cnt = (ci == 7) ? 7 : 6;
    for (int l = 0; l < cnt * 2; ++l) {
      int u = l * 256 + t;  // 512 f4 per row
      int row = ci * 6 + (u >> 9), c = u & 511;
      int srow = (row == 0) ? 0 : (256 + row);
      int drow = (row == 0) ? 0 : (128 + row);
      *(float4*)(out0 + ((size_t)b * SOUT + drow) * DIM + (size_t)c * 4) =
          *(const float4*)(tokens + ((size_t)b * SEQ + srow) * DIM + (size_t)c * 4);
    }
    return;
  }

  const int dci = blockIdx.x;
  const int lane = t & 63;
  const int wid = t >> 6;          // 0..3: m-rows wid*64..wid*64+63
  const int fr = lane & 15;        // fragment minor index
  const int g0 = (lane >> 4) * 2;  // d-group: d0 = (lane>>4)*8 = g0*4

  __shared__ __align__(16) KSMem sm;

  const float* pbase = tokens + ((size_t)b * SEQ + 1) * DIM + (size_t)dci * dchunk;
  const float* tbase = tokens + ((size_t)b * SEQ + 1 + NP) * DIM + (size_t)dci * dchunk;

  float4 st[10];
  f32x4 acc[4][3];
#pragma unroll
  for (int mf = 0; mf < 4; ++mf)
#pragma unroll
    for (int nf = 0; nf < 3; ++nf) acc[mf][nf] = (f32x4){0.f, 0.f, 0.f, 0.f};
  float ssqa[10] = {};
  const int nchunk = dchunk / 32;

  // staging map: u = t + 256*l. u<2048: p-row u>>3, c8=u&7;
  // 2048<=u<2432: task row (u-2048)>>3 (stored at 256+row).
  auto gload = [&](int ck) {
#pragma unroll
    for (int l = 0; l < 10; ++l) {
      int u = t + 256 * l;
      if (u < 2048) {
        int row = u >> 3, c8 = u & 7;
        st[l] = *(const float4*)(pbase + (size_t)row * DIM + ck * 32 + c8 * 4);
      } else if (u < 2432) {
        int v = u - 2048;
        int row = v >> 3, c8 = v & 7;
        st[l] = *(const float4*)(tbase + (size_t)row * DIM + ck * 32 + c8 * 4);
      }
    }
  };
  auto lwrite = [&]() {
#pragma unroll
    for (int l = 0; l < 10; ++l) {
      int u = t + 256 * l;
      if (u < 2432) {
        int row, c8;
        if (u < 2048) {
          row = u >> 3;
          c8 = u & 7;
        } else {
          row = 256 + ((u - 2048) >> 3);
          c8 = (u - 2048) & 7;
        }
        float4 v = st[l];
        f16 h0 = (f16)v.x, h1 = (f16)v.y, h2 = (f16)v.z, h3 = (f16)v.w;
        f16 e0 = (f16)(v.x - (float)h0), e1 = (f16)(v.y - (float)h1),
            e2 = (f16)(v.z - (float)h2), e3 = (f16)(v.w - (float)h3);
        f16x8 pk = {h0, h1, h2, h3, e0, e1, e2, e3};
        *(f16x8*)&sm.stage[row * 72 + c8 * 8] = pk;
        ssqa[l] += v.x * v.x + v.y * v.y + v.z * v.z + v.w * v.w;
      }
    }
  };

  gload(0);
  for (int ck = 0; ck < nchunk; ++ck) {
    __syncthreads();  // previous compute done reading stage
    lwrite();
    if (ck + 1 < nchunk) gload(ck + 1);  // prefetch overlaps compute
    __syncthreads();

    f16x8 bh[3], bl[3];
#pragma unroll
    for (int nf = 0; nf < 3; ++nf) {
      const f16* rowp = &sm.stage[(256 + nf * 16 + fr) * 72];
      f16x8 v1 = *(const f16x8*)(rowp + g0 * 8);
      f16x8 v2 = *(const f16x8*)(rowp + g0 * 8 + 8);
      bh[nf] = __builtin_shufflevector(v1, v2, 0, 1, 2, 3, 8, 9, 10, 11);
      bl[nf] = __builtin_shufflevector(v1, v2, 4, 5, 6, 7, 12, 13, 14, 15);
    }
#pragma unroll
    for (int mf = 0; mf < 4; ++mf) {
      const f16* rowp = &sm.stage[(wid * 64 + mf * 16 + fr) * 72];
      f16x8 v1 = *(const f16x8*)(rowp + g0 * 8);
      f16x8 v2 = *(const f16x8*)(rowp + g0 * 8 + 8);
      f16x8 ah = __builtin_shufflevector(v1, v2, 0, 1, 2, 3, 8, 9, 10, 11);
      f16x8 al = __builtin_shufflevector(v1, v2, 4, 5, 6, 7, 12, 13, 14, 15);
#pragma unroll
      for (int nf = 0; nf < 3; ++nf) {
        acc[mf][nf] =
            __builtin_amdgcn_mfma_f32_16x16x32_f16(ah, bh[nf], acc[mf][nf], 0, 0, 0);
        acc[mf][nf] =
            __builtin_amdgcn_mfma_f32_16x16x32_f16(ah, bl[nf], acc[mf][nf], 0, 0, 0);
        acc[mf][nf] =
            __builtin_amdgcn_mfma_f32_16x16x32_f16(al, bh[nf], acc[mf][nf], 0, 0, 0);
      }
    }
  }

  // epilogue: acc -> LDS rt (stage no longer needed), then coalesced stores
  __syncthreads();
#pragma unroll
  for (int mf = 0; mf < 4; ++mf)
#pragma unroll
    for (int nf = 0; nf < 3; ++nf) {
      int trow = nf * 16 + fr;                          // D col = lane&15 -> t
      int pcol = wid * 64 + mf * 16 + (lane >> 4) * 4;  // D row -> p (4 regs)
      *(float4*)&sm.rt[trow * 260 + pcol] = *(float4*)&acc[mf][nf];
    }
  __syncthreads();
  float* rp = rpart + ((size_t)b * ndc + dci) * (NT * NP);
#pragma unroll
  for (int i = 0; i < 12; ++i) {
    int f = i * 1024 + t * 4;  // 0..12287, coalesced
    int row = f >> 8, col = f & 255;
    *(float4*)(rp + f) = *(float4*)&sm.rt[row * 260 + col];
  }

  // ssq: reduce across the 8 staging lanes of each row (fixed order)
#pragma unroll
  for (int l = 0; l < 10; ++l) {
    float s = ssqa[l];
    s += __shfl_down(s, 4, 8);
    s += __shfl_down(s, 2, 8);
    s += __shfl_down(s, 1, 8);
    ssqa[l] = s;
  }
  if ((t & 7) == 0) {
#pragma unroll
    for (int l = 0; l < 10; ++l) {
      int u = t + 256 * l;
      if (u < 2048) {
        ssqP[((size_t)b * ndc + dci) * NP + (u >> 3)] = ssqa[l];
      } else if (u < 2432) {
        ssqT[((size_t)b * ndc + dci) * NT + ((u - 2048) >> 3)] = ssqa[l];
      }
    }
  }
}

// ---------------------------------------------------------------------------
// K1b: grid (16 pt, 64 b) x 256 thr, 16-row tiles. Sum ndc partials in fixed
// dci order (deterministic), rms + softmax, write attnp = softmax*invT and
// rn = raw*invP. Inits umax.
// ---------------------------------------------------------------------------
__global__ __launch_bounds__(256) void k1b_reduce_softmax(
    const float* __restrict__ rpart, const float* __restrict__ ssqP,
    const float* __restrict__ ssqT, float* __restrict__ attnp,
    float* __restrict__ rn, unsigned long long* __restrict__ umax, int ndc) {
  const int pt = blockIdx.x;  // rows pt*16..pt*16+15
  const int b = blockIdx.y;
  const int t = threadIdx.x;
  const int r = t >> 4;    // 0..15
  const int c16 = t & 15;  // cols c16*3..c16*3+2

  __shared__ float L[16][49];
  __shared__ float invPs[16];
  __shared__ float invTs[48];

  float a[3] = {};
  const float* rb = rpart + (size_t)b * ndc * (NT * NP) + pt * 16 + r;
  for (int dci = 0; dci < ndc; ++dci) {
    const float* rp = rb + (size_t)dci * (NT * NP);
#pragma unroll
    for (int k = 0; k < 3; ++k) a[k] += rp[(c16 * 3 + k) * NP];
  }
#pragma unroll
  for (int k = 0; k < 3; ++k) L[r][c16 * 3 + k] = a[k];

  if (t < 16) {
    float s = 0.f;
    for (int dci = 0; dci < ndc; ++dci)
      s += ssqP[((size_t)b * ndc + dci) * NP + pt * 16 + t];
    invPs[t] = 1.0f / sqrtf(s * (1.0f / 2048.0f) + 1e-6f);
    umax[(size_t)b * NP + pt * 16 + t] = 0ull;
  } else if (t < 64) {
    int j = t - 16;
    float s = 0.f;
    for (int dci = 0; dci < ndc; ++dci)
      s += ssqT[((size_t)b * ndc + dci) * NT + j];
    invTs[j] = 1.0f / sqrtf(s * (1.0f / 2048.0f) + 1e-6f);
  }
  __syncthreads();

  if (t < 16) {
    const float invp = invPs[t];
    float lg[48];
    float m = -3.4e38f;
#pragma unroll
    for (int j = 0; j < 48; ++j) {
      lg[j] = L[t][j] * invp * invTs[j] * kScale;
      m = fmaxf(m, lg[j]);
    }
    float s = 0.f;
#pragma unroll
    for (int j = 0; j < 48; ++j) {
      lg[j] = expf(lg[j] - m);
      s += lg[j];
    }
    const float is = 1.0f / s;
    float* ao = attnp + ((size_t)b * NP + pt * 16 + t) * NT;
    float* ro = rn + ((size_t)b * NP + pt * 16 + t) * NT;
#pragma unroll
    for (int j = 0; j < 48; ++j) ao[j] = lg[j] * is * invTs[j];
#pragma unroll
    for (int j = 0; j < 48; ++j) ro[j] = L[t][j] * invp;
  }
}

// ---------------------------------------------------------------------------
// K2: score[p][q] = sum_t attn'[p][t] * Rn[q][t], argmax over q folded in via
// packed (mono-float | ~q) atomicMax (order-independent -> deterministic).
// k-loop unroll capped at 6 (VGPR 256 -> ~110, R17: -50 us).
// ---------------------------------------------------------------------------
__global__ __launch_bounds__(256) void k2_score_argmax(
    const float* __restrict__ attnp, const float* __restrict__ rn,
    unsigned long long* __restrict__ umax) {
  const int b = blockIdx.y;
  const int qt = blockIdx.x & 3;
  const int pb = blockIdx.x >> 2;
  const int t = threadIdx.x;
  const int tp = t >> 4, tq = t & 15;

  __shared__ float aS[48][68];
  __shared__ float rS[48][68];

  const float* ab = attnp + ((size_t)b * NP + pb * 64) * NT;
  const float* rb = rn + ((size_t)b * NP + qt * 64) * NT;
#pragma unroll
  for (int l = 0; l < 3; ++l) {
    int u = t + 256 * l;  // 64 rows x 12 f4
    int row = u / 12, c4 = u % 12;
    float4 v = *(const float4*)(ab + (size_t)row * NT + c4 * 4);
    aS[c4 * 4 + 0][row] = v.x;
    aS[c4 * 4 + 1][row] = v.y;
    aS[c4 * 4 + 2][row] = v.z;
    aS[c4 * 4 + 3][row] = v.w;
    float4 wv = *(const float4*)(rb + (size_t)row * NT + c4 * 4);
    rS[c4 * 4 + 0][row] = wv.x;
    rS[c4 * 4 + 1][row] = wv.y;
    rS[c4 * 4 + 2][row] = wv.z;
    rS[c4 * 4 + 3][row] = wv.w;
  }
  __syncthreads();

  float acc[4][4] = {};
#pragma unroll 6
  for (int k = 0; k < 48; ++k) {
    float4 av = *(const float4*)&aS[k][tp * 4];
    float4 rv = *(const float4*)&rS[k][tq * 4];
    float aa[4] = {av.x, av.y, av.z, av.w};
    float rr[4] = {rv.x, rv.y, rv.z, rv.w};
#pragma unroll
    for (int i = 0; i < 4; ++i)
#pragma unroll
      for (int j = 0; j < 4; ++j) acc[i][j] += aa[i] * rr[j];
  }

#pragma unroll
  for (int i = 0; i < 4; ++i) {
    float bs = acc[i][0];
    int bq = qt * 64 + tq * 4;
#pragma unroll
    for (int j = 1; j < 4; ++j) {
      float s = acc[i][j];
      int qq = qt * 64 + tq * 4 + j;
      if (s > bs) {  // strict > keeps smallest q on ties
        bs = s;
        bq = qq;
      }
    }
    unsigned us = __float_as_uint(bs);
    us = (us & 0x80000000u) ? ~us : (us | 0x80000000u);
    unsigned long long key =
        ((unsigned long long)us << 32) | (unsigned long long)(0xFFFFFFFFu - (unsigned)bq);
    for (int o = 8; o >= 1; o >>= 1) {
      unsigned long long ok = __shfl_xor(key, o, 16);
      if (ok > key) key = ok;
    }
    if (tq == 0) atomicMax(&umax[(size_t)b * NP + pb * 64 + tp * 4 + i], key);
  }
}

// ---------------------------------------------------------------------------
// K3: per batch: decode argmax, vote counts, exact rank (count desc, idx asc),
// keep rank<128, emit ascending; gather pos/mask in the same block.
// ---------------------------------------------------------------------------
__global__ __launch_bounds__(256) void k3_select_meta(
    const unsigned long long* __restrict__ umax, const int* __restrict__ pos,
    const int* __restrict__ msk, int* __restrict__ order,
    float* __restrict__ out1, float* __restrict__ out2) {
  const int b = blockIdx.x, t = threadIdx.x;
  __shared__ int cnt[256];
  __shared__ int kept[256];
  __shared__ int sorder[NKEEP];
  cnt[t] = 0;
  __syncthreads();
  unsigned long long key = umax[(size_t)b * NP + t];
  int q = (int)(0xFFFFFFFFu - (unsigned)(key & 0xFFFFFFFFull));
  atomicAdd(&cnt[q], 1);
  __syncthreads();
  const int c = cnt[t];
  int rank = 0;
  for (int u = 0; u < 256; ++u) {
    int cu = cnt[u];
    rank += (cu > c || (cu == c && u < t)) ? 1 : 0;
  }
  kept[t] = (rank < NKEEP) ? 1 : 0;
  __syncthreads();
  if (kept[t]) {
    int posn = 0;
    for (int u = 0; u < t; ++u) posn += kept[u];
    order[b * NKEEP + posn] = t;
    sorder[posn] = t;
  }
  __syncthreads();
  if (t < SOUT) {
    int src;
    if (t == 0) src = 0;
    else if (t < 1 + NKEEP) src = 1 + sorder[t - 1];
    else src = t + (NP - NKEEP);
    out1[b * SOUT + t] = (float)pos[b * SEQ + src];
    out2[b * SOUT + t] = (float)msk[b * SEQ + src];
  }
}

// ---------------------------------------------------------------------------
// K4: gather only the 128 kept patch rows (cls/task copied in k1a).
// ---------------------------------------------------------------------------
__global__ __launch_bounds__(256) void k4_gather_kept(
    const float* __restrict__ tokens, const int* __restrict__ order,
    float* __restrict__ out) {
  const int ki = blockIdx.x;  // 0..127
  const int b = blockIdx.y;
  const int t = threadIdx.x;
  const int src = 1 + order[b * NKEEP + ki];
  const float4* in4 = (const float4*)(tokens + ((size_t)b * SEQ + src) * DIM);
  float4* o4 = (float4*)(out + ((size_t)b * SOUT + 1 + ki) * DIM);
  o4[t] = in4[t];
  o4[t + 256] = in4[t + 256];
}

// ---------------------------------------------------------------------------
extern "C" void kernel_launch(void* const* d_in, const int* in_sizes, int n_in,
                              void* d_out, int out_size, void* d_ws,
                              size_t ws_size, hipStream_t stream) {
  const float* tokens = (const float*)d_in[0];
  const int* pos = (const int*)d_in[1];
  const int* msk = (const int*)d_in[2];

  float* out0 = (float*)d_out;
  float* out1 = out0 + (size_t)NB * SOUT * DIM;
  float* out2 = out1 + (size_t)NB * SOUT;

  // split-K depth (shrink if workspace is tight)
  const size_t fixed = (size_t)(2 * NB * NP * NT) * 4 + (size_t)NB * NP * 8 +
                       (size_t)NB * NKEEP * 4;
  const size_t perndc = (size_t)NB * (NT * NP + NP + NT) * 4;
  int ndc = 16;
  while (ndc > 2 && fixed + (size_t)ndc * perndc > ws_size) ndc >>= 1;
  const int dchunk = DIM / ndc;

  char* ws = (char*)d_ws;
  float* attnp = (float*)ws;                 // NB*NP*NT
  float* rn = attnp + (size_t)NB * NP * NT;  // NB*NP*NT
  unsigned long long* umax = (unsigned long long*)(rn + (size_t)NB * NP * NT);
  int* order = (int*)(umax + (size_t)NB * NP);
  float* rpart = (float*)(order + (size_t)NB * NKEEP);  // NB*ndc*48*256
  float* ssqP = rpart + (size_t)NB * ndc * NT * NP;     // NB*ndc*256
  float* ssqT = ssqP + (size_t)NB * ndc * NP;           // NB*ndc*48

  k1a_partial_gemm<<<dim3(ndc + NCOPY, NB), 256, 0, stream>>>(
      tokens, rpart, ssqP, ssqT, out0, ndc, dchunk);
  k1b_reduce_softmax<<<dim3(16, NB), 256, 0, stream>>>(rpart, ssqP, ssqT, attnp,
                                                       rn, umax, ndc);
  k2_score_argmax<<<dim3(16, NB), 256, 0, stream>>>(attnp, rn, umax);
  k3_select_meta<<<NB, 256, 0, stream>>>(umax, pos, msk, order, out1, out2);
  k4_gather_kept<<<dim3(NKEEP, NB), 256, 0, stream>>>(tokens, order, out0);
}

// Round 19
// 120.296 us; speedup vs baseline: 1.1074x; 1.1074x over previous
//
#include <hip/hip_runtime.h>

#define NB 64      // batch
#define SEQ 305    // sequence length
#define DIM 2048   // hidden
#define NP 256     // patches
#define NT 48      // task tokens
#define NKEEP 128  // kept patches
#define SOUT 177   // 1 + 128 + 48
#define NCOPY 8    // copy blocks per batch

static_assert(1 + NP + NT == SEQ, "layout");

constexpr float kScale = 0.022097086912079608f;  // 1/sqrt(2048)

typedef _Float16 f16;
typedef __attribute__((ext_vector_type(8))) _Float16 f16x8;
typedef __attribute__((ext_vector_type(4))) float f32x4;

// ---------------------------------------------------------------------------
// K1a: split-f16 MFMA partial GEMM (R13/R15/R17-validated, depth-1 staging,
// ndc=8 -- R18 measured ndc=16 as -13 us regression). grid (ndc+NCOPY, 64),
// 256 thr. x < ndc: GEMM over D chunk dci=x. x >= ndc: 1/8 of the static
// cls+task copy (overlaps with GEMM). Per K32 chunk: fp32 -> (hi,lo) f16
// split into interleaved {hi4,lo4} LDS groups (b128 writes, conflict-free),
// then per wave 4x3 fragments x 3 MFMAs (hh, hl, lh) into f32 acc.
// Error ~5e-7 relative -- proven selection-exact R13-R18 (absmax = 0).
// ---------------------------------------------------------------------------
union KSMem {
  f16 stage[304 * 72];   // 43,776 B
  float rt[48 * 260];    // 49,920 B
};

__global__ __launch_bounds__(256) void k1a_partial_gemm(
    const float* __restrict__ tokens, float* __restrict__ rpart,
    float* __restrict__ ssqP, float* __restrict__ ssqT,
    float* __restrict__ out0, int ndc, int dchunk) {
  const int b = blockIdx.y;
  const int t = threadIdx.x;

  if ((int)blockIdx.x >= ndc) {
    // copy cls (row 0 -> 0) and task rows (257..304 -> 129..176), 49 rows
    // split 6/.../7 across NCOPY blocks.
    const int ci = blockIdx.x - ndc;  // 0..7
    const int cnt = (ci == 7) ? 7 : 6;
    for (int l = 0; l < cnt * 2; ++l) {
      int u = l * 256 + t;  // 512 f4 per row
      int row = ci * 6 + (u >> 9), c = u & 511;
      int srow = (row == 0) ? 0 : (256 + row);
      int drow = (row == 0) ? 0 : (128 + row);
      *(float4*)(out0 + ((size_t)b * SOUT + drow) * DIM + (size_t)c * 4) =
          *(const float4*)(tokens + ((size_t)b * SEQ + srow) * DIM + (size_t)c * 4);
    }
    return;
  }

  const int dci = blockIdx.x;
  const int lane = t & 63;
  const int wid = t >> 6;          // 0..3: m-rows wid*64..wid*64+63
  const int fr = lane & 15;        // fragment minor index
  const int g0 = (lane >> 4) * 2;  // d-group: d0 = (lane>>4)*8 = g0*4

  __shared__ __align__(16) KSMem sm;

  const float* pbase = tokens + ((size_t)b * SEQ + 1) * DIM + (size_t)dci * dchunk;
  const float* tbase = tokens + ((size_t)b * SEQ + 1 + NP) * DIM + (size_t)dci * dchunk;

  float4 st[10];
  f32x4 acc[4][3];
#pragma unroll
  for (int mf = 0; mf < 4; ++mf)
#pragma unroll
    for (int nf = 0; nf < 3; ++nf) acc[mf][nf] = (f32x4){0.f, 0.f, 0.f, 0.f};
  float ssqa[10] = {};
  const int nchunk = dchunk / 32;

  // staging map: u = t + 256*l. u<2048: p-row u>>3, c8=u&7;
  // 2048<=u<2432: task row (u-2048)>>3 (stored at 256+row).
  auto gload = [&](int ck) {
#pragma unroll
    for (int l = 0; l < 10; ++l) {
      int u = t + 256 * l;
      if (u < 2048) {
        int row = u >> 3, c8 = u & 7;
        st[l] = *(const float4*)(pbase + (size_t)row * DIM + ck * 32 + c8 * 4);
      } else if (u < 2432) {
        int v = u - 2048;
        int row = v >> 3, c8 = v & 7;
        st[l] = *(const float4*)(tbase + (size_t)row * DIM + ck * 32 + c8 * 4);
      }
    }
  };
  auto lwrite = [&]() {
#pragma unroll
    for (int l = 0; l < 10; ++l) {
      int u = t + 256 * l;
      if (u < 2432) {
        int row, c8;
        if (u < 2048) {
          row = u >> 3;
          c8 = u & 7;
        } else {
          row = 256 + ((u - 2048) >> 3);
          c8 = (u - 2048) & 7;
        }
        float4 v = st[l];
        f16 h0 = (f16)v.x, h1 = (f16)v.y, h2 = (f16)v.z, h3 = (f16)v.w;
        f16 e0 = (f16)(v.x - (float)h0), e1 = (f16)(v.y - (float)h1),
            e2 = (f16)(v.z - (float)h2), e3 = (f16)(v.w - (float)h3);
        f16x8 pk = {h0, h1, h2, h3, e0, e1, e2, e3};
        *(f16x8*)&sm.stage[row * 72 + c8 * 8] = pk;
        ssqa[l] += v.x * v.x + v.y * v.y + v.z * v.z + v.w * v.w;
      }
    }
  };

  gload(0);
  for (int ck = 0; ck < nchunk; ++ck) {
    __syncthreads();  // previous compute done reading stage
    lwrite();
    if (ck + 1 < nchunk) gload(ck + 1);  // prefetch overlaps compute
    __syncthreads();

    f16x8 bh[3], bl[3];
#pragma unroll
    for (int nf = 0; nf < 3; ++nf) {
      const f16* rowp = &sm.stage[(256 + nf * 16 + fr) * 72];
      f16x8 v1 = *(const f16x8*)(rowp + g0 * 8);
      f16x8 v2 = *(const f16x8*)(rowp + g0 * 8 + 8);
      bh[nf] = __builtin_shufflevector(v1, v2, 0, 1, 2, 3, 8, 9, 10, 11);
      bl[nf] = __builtin_shufflevector(v1, v2, 4, 5, 6, 7, 12, 13, 14, 15);
    }
#pragma unroll
    for (int mf = 0; mf < 4; ++mf) {
      const f16* rowp = &sm.stage[(wid * 64 + mf * 16 + fr) * 72];
      f16x8 v1 = *(const f16x8*)(rowp + g0 * 8);
      f16x8 v2 = *(const f16x8*)(rowp + g0 * 8 + 8);
      f16x8 ah = __builtin_shufflevector(v1, v2, 0, 1, 2, 3, 8, 9, 10, 11);
      f16x8 al = __builtin_shufflevector(v1, v2, 4, 5, 6, 7, 12, 13, 14, 15);
#pragma unroll
      for (int nf = 0; nf < 3; ++nf) {
        acc[mf][nf] =
            __builtin_amdgcn_mfma_f32_16x16x32_f16(ah, bh[nf], acc[mf][nf], 0, 0, 0);
        acc[mf][nf] =
            __builtin_amdgcn_mfma_f32_16x16x32_f16(ah, bl[nf], acc[mf][nf], 0, 0, 0);
        acc[mf][nf] =
            __builtin_amdgcn_mfma_f32_16x16x32_f16(al, bh[nf], acc[mf][nf], 0, 0, 0);
      }
    }
  }

  // epilogue: acc -> LDS rt (stage no longer needed), then coalesced stores
  __syncthreads();
#pragma unroll
  for (int mf = 0; mf < 4; ++mf)
#pragma unroll
    for (int nf = 0; nf < 3; ++nf) {
      int trow = nf * 16 + fr;                          // D col = lane&15 -> t
      int pcol = wid * 64 + mf * 16 + (lane >> 4) * 4;  // D row -> p (4 regs)
      *(float4*)&sm.rt[trow * 260 + pcol] = *(float4*)&acc[mf][nf];
    }
  __syncthreads();
  float* rp = rpart + ((size_t)b * ndc + dci) * (NT * NP);
#pragma unroll
  for (int i = 0; i < 12; ++i) {
    int f = i * 1024 + t * 4;  // 0..12287, coalesced
    int row = f >> 8, col = f & 255;
    *(float4*)(rp + f) = *(float4*)&sm.rt[row * 260 + col];
  }

  // ssq: reduce across the 8 staging lanes of each row (fixed order)
#pragma unroll
  for (int l = 0; l < 10; ++l) {
    float s = ssqa[l];
    s += __shfl_down(s, 4, 8);
    s += __shfl_down(s, 2, 8);
    s += __shfl_down(s, 1, 8);
    ssqa[l] = s;
  }
  if ((t & 7) == 0) {
#pragma unroll
    for (int l = 0; l < 10; ++l) {
      int u = t + 256 * l;
      if (u < 2048) {
        ssqP[((size_t)b * ndc + dci) * NP + (u >> 3)] = ssqa[l];
      } else if (u < 2432) {
        ssqT[((size_t)b * ndc + dci) * NT + ((u - 2048) >> 3)] = ssqa[l];
      }
    }
  }
}

// ---------------------------------------------------------------------------
// K1b: grid (16 pt, 64 b) x 256 thr, 16-row tiles. Sum ndc partials in fixed
// dci order (deterministic), rms + softmax, write attnp = softmax*invT and
// rn = raw*invP. Inits umax.
// ---------------------------------------------------------------------------
__global__ __launch_bounds__(256) void k1b_reduce_softmax(
    const float* __restrict__ rpart, const float* __restrict__ ssqP,
    const float* __restrict__ ssqT, float* __restrict__ attnp,
    float* __restrict__ rn, unsigned long long* __restrict__ umax, int ndc) {
  const int pt = blockIdx.x;  // rows pt*16..pt*16+15
  const int b = blockIdx.y;
  const int t = threadIdx.x;
  const int r = t >> 4;    // 0..15
  const int c16 = t & 15;  // cols c16*3..c16*3+2

  __shared__ float L[16][49];
  __shared__ float invPs[16];
  __shared__ float invTs[48];

  float a[3] = {};
  const float* rb = rpart + (size_t)b * ndc * (NT * NP) + pt * 16 + r;
  for (int dci = 0; dci < ndc; ++dci) {
    const float* rp = rb + (size_t)dci * (NT * NP);
#pragma unroll
    for (int k = 0; k < 3; ++k) a[k] += rp[(c16 * 3 + k) * NP];
  }
#pragma unroll
  for (int k = 0; k < 3; ++k) L[r][c16 * 3 + k] = a[k];

  if (t < 16) {
    float s = 0.f;
    for (int dci = 0; dci < ndc; ++dci)
      s += ssqP[((size_t)b * ndc + dci) * NP + pt * 16 + t];
    invPs[t] = 1.0f / sqrtf(s * (1.0f / 2048.0f) + 1e-6f);
    umax[(size_t)b * NP + pt * 16 + t] = 0ull;
  } else if (t < 64) {
    int j = t - 16;
    float s = 0.f;
    for (int dci = 0; dci < ndc; ++dci)
      s += ssqT[((size_t)b * ndc + dci) * NT + j];
    invTs[j] = 1.0f / sqrtf(s * (1.0f / 2048.0f) + 1e-6f);
  }
  __syncthreads();

  if (t < 16) {
    const float invp = invPs[t];
    float lg[48];
    float m = -3.4e38f;
#pragma unroll
    for (int j = 0; j < 48; ++j) {
      lg[j] = L[t][j] * invp * invTs[j] * kScale;
      m = fmaxf(m, lg[j]);
    }
    float s = 0.f;
#pragma unroll
    for (int j = 0; j < 48; ++j) {
      lg[j] = expf(lg[j] - m);
      s += lg[j];
    }
    const float is = 1.0f / s;
    float* ao = attnp + ((size_t)b * NP + pt * 16 + t) * NT;
    float* ro = rn + ((size_t)b * NP + pt * 16 + t) * NT;
#pragma unroll
    for (int j = 0; j < 48; ++j) ao[j] = lg[j] * is * invTs[j];
#pragma unroll
    for (int j = 0; j < 48; ++j) ro[j] = L[t][j] * invp;
  }
}

// ---------------------------------------------------------------------------
// K2: score[p][q] = sum_t attn'[p][t] * Rn[q][t], argmax over q folded in via
// packed (mono-float | ~q) atomicMax (order-independent -> deterministic).
// k-loop unroll capped at 6 (VGPR 256 -> ~110, R17: -50 us).
// ---------------------------------------------------------------------------
__global__ __launch_bounds__(256) void k2_score_argmax(
    const float* __restrict__ attnp, const float* __restrict__ rn,
    unsigned long long* __restrict__ umax) {
  const int b = blockIdx.y;
  const int qt = blockIdx.x & 3;
  const int pb = blockIdx.x >> 2;
  const int t = threadIdx.x;
  const int tp = t >> 4, tq = t & 15;

  __shared__ float aS[48][68];
  __shared__ float rS[48][68];

  const float* ab = attnp + ((size_t)b * NP + pb * 64) * NT;
  const float* rb = rn + ((size_t)b * NP + qt * 64) * NT;
#pragma unroll
  for (int l = 0; l < 3; ++l) {
    int u = t + 256 * l;  // 64 rows x 12 f4
    int row = u / 12, c4 = u % 12;
    float4 v = *(const float4*)(ab + (size_t)row * NT + c4 * 4);
    aS[c4 * 4 + 0][row] = v.x;
    aS[c4 * 4 + 1][row] = v.y;
    aS[c4 * 4 + 2][row] = v.z;
    aS[c4 * 4 + 3][row] = v.w;
    float4 wv = *(const float4*)(rb + (size_t)row * NT + c4 * 4);
    rS[c4 * 4 + 0][row] = wv.x;
    rS[c4 * 4 + 1][row] = wv.y;
    rS[c4 * 4 + 2][row] = wv.z;
    rS[c4 * 4 + 3][row] = wv.w;
  }
  __syncthreads();

  float acc[4][4] = {};
#pragma unroll 6
  for (int k = 0; k < 48; ++k) {
    float4 av = *(const float4*)&aS[k][tp * 4];
    float4 rv = *(const float4*)&rS[k][tq * 4];
    float aa[4] = {av.x, av.y, av.z, av.w};
    float rr[4] = {rv.x, rv.y, rv.z, rv.w};
#pragma unroll
    for (int i = 0; i < 4; ++i)
#pragma unroll
      for (int j = 0; j < 4; ++j) acc[i][j] += aa[i] * rr[j];
  }

#pragma unroll
  for (int i = 0; i < 4; ++i) {
    float bs = acc[i][0];
    int bq = qt * 64 + tq * 4;
#pragma unroll
    for (int j = 1; j < 4; ++j) {
      float s = acc[i][j];
      int qq = qt * 64 + tq * 4 + j;
      if (s > bs) {  // strict > keeps smallest q on ties
        bs = s;
        bq = qq;
      }
    }
    unsigned us = __float_as_uint(bs);
    us = (us & 0x80000000u) ? ~us : (us | 0x80000000u);
    unsigned long long key =
        ((unsigned long long)us << 32) | (unsigned long long)(0xFFFFFFFFu - (unsigned)bq);
    for (int o = 8; o >= 1; o >>= 1) {
      unsigned long long ok = __shfl_xor(key, o, 16);
      if (ok > key) key = ok;
    }
    if (tq == 0) atomicMax(&umax[(size_t)b * NP + pb * 64 + tp * 4 + i], key);
  }
}

// ---------------------------------------------------------------------------
// K3: per batch: decode argmax, vote counts, exact rank (count desc, idx asc),
// keep rank<128, emit ascending; gather pos/mask in the same block.
// ---------------------------------------------------------------------------
__global__ __launch_bounds__(256) void k3_select_meta(
    const unsigned long long* __restrict__ umax, const int* __restrict__ pos,
    const int* __restrict__ msk, int* __restrict__ order,
    float* __restrict__ out1, float* __restrict__ out2) {
  const int b = blockIdx.x, t = threadIdx.x;
  __shared__ int cnt[256];
  __shared__ int kept[256];
  __shared__ int sorder[NKEEP];
  cnt[t] = 0;
  __syncthreads();
  unsigned long long key = umax[(size_t)b * NP + t];
  int q = (int)(0xFFFFFFFFu - (unsigned)(key & 0xFFFFFFFFull));
  atomicAdd(&cnt[q], 1);
  __syncthreads();
  const int c = cnt[t];
  int rank = 0;
  for (int u = 0; u < 256; ++u) {
    int cu = cnt[u];
    rank += (cu > c || (cu == c && u < t)) ? 1 : 0;
  }
  kept[t] = (rank < NKEEP) ? 1 : 0;
  __syncthreads();
  if (kept[t]) {
    int posn = 0;
    for (int u = 0; u < t; ++u) posn += kept[u];
    order[b * NKEEP + posn] = t;
    sorder[posn] = t;
  }
  __syncthreads();
  if (t < SOUT) {
    int src;
    if (t == 0) src = 0;
    else if (t < 1 + NKEEP) src = 1 + sorder[t - 1];
    else src = t + (NP - NKEEP);
    out1[b * SOUT + t] = (float)pos[b * SEQ + src];
    out2[b * SOUT + t] = (float)msk[b * SEQ + src];
  }
}

// ---------------------------------------------------------------------------
// K4: gather only the 128 kept patch rows (cls/task copied in k1a).
// ---------------------------------------------------------------------------
__global__ __launch_bounds__(256) void k4_gather_kept(
    const float* __restrict__ tokens, const int* __restrict__ order,
    float* __restrict__ out) {
  const int ki = blockIdx.x;  // 0..127
  const int b = blockIdx.y;
  const int t = threadIdx.x;
  const int src = 1 + order[b * NKEEP + ki];
  const float4* in4 = (const float4*)(tokens + ((size_t)b * SEQ + src) * DIM);
  float4* o4 = (float4*)(out + ((size_t)b * SOUT + 1 + ki) * DIM);
  o4[t] = in4[t];
  o4[t + 256] = in4[t + 256];
}

// ---------------------------------------------------------------------------
extern "C" void kernel_launch(void* const* d_in, const int* in_sizes, int n_in,
                              void* d_out, int out_size, void* d_ws,
                              size_t ws_size, hipStream_t stream) {
  const float* tokens = (const float*)d_in[0];
  const int* pos = (const int*)d_in[1];
  const int* msk = (const int*)d_in[2];

  float* out0 = (float*)d_out;
  float* out1 = out0 + (size_t)NB * SOUT * DIM;
  float* out2 = out1 + (size_t)NB * SOUT;

  // split-K depth (shrink if workspace is tight)
  const size_t fixed = (size_t)(2 * NB * NP * NT) * 4 + (size_t)NB * NP * 8 +
                       (size_t)NB * NKEEP * 4;
  const size_t perndc = (size_t)NB * (NT * NP + NP + NT) * 4;
  int ndc = 8;
  while (ndc > 2 && fixed + (size_t)ndc * perndc > ws_size) ndc >>= 1;
  const int dchunk = DIM / ndc;

  char* ws = (char*)d_ws;
  float* attnp = (float*)ws;                 // NB*NP*NT
  float* rn = attnp + (size_t)NB * NP * NT;  // NB*NP*NT
  unsigned long long* umax = (unsigned long long*)(rn + (size_t)NB * NP * NT);
  int* order = (int*)(umax + (size_t)NB * NP);
  float* rpart = (float*)(order + (size_t)NB * NKEEP);  // NB*ndc*48*256
  float* ssqP = rpart + (size_t)NB * ndc * NT * NP;     // NB*ndc*256
  float* ssqT = ssqP + (size_t)NB * ndc * NP;           // NB*ndc*48

  k1a_partial_gemm<<<dim3(ndc + NCOPY, NB), 256, 0, stream>>>(
      tokens, rpart, ssqP, ssqT, out0, ndc, dchunk);
  k1b_reduce_softmax<<<dim3(16, NB), 256, 0, stream>>>(rpart, ssqP, ssqT, attnp,
                                                       rn, umax, ndc);
  k2_score_argmax<<<dim3(16, NB), 256, 0, stream>>>(attnp, rn, umax);
  k3_select_meta<<<NB, 256, 0, stream>>>(umax, pos, msk, order, out1, out2);
  k4_gather_kept<<<dim3(NKEEP, NB), 256, 0, stream>>>(tokens, order, out0);
}